// Round 4
// baseline (139.843 us; speedup 1.0000x reference)
//
#include <hip/hip_runtime.h>
#include <stdint.h>

#define B_  4096
#define F_  512
#define T_  2048
#define D_  4
#define M_  (T_ * D_)   // 8192 GEMM-M (trees*dims)
#define KC_ (F_ / 8)    // 64 16-byte k-chunks per row
#define TAU 0.2018004745467103f

typedef __attribute__((ext_vector_type(8)))  short bf16x8;
typedef __attribute__((ext_vector_type(16))) float f32x16;

static __device__ __forceinline__ unsigned short f2bf(float f) {
  union { float f; uint32_t u; } v; v.f = f;
  uint32_t r = v.u + 0x7fffu + ((v.u >> 16) & 1u);  // RNE
  return (unsigned short)(r >> 16);
}

// ---------------------------------------------------------------------------
// Prep (single launch, two jobs by blockIdx):
//  blocks [0,1024):      x (B,F) fp32 -> xbF frag-major bf16: cell(kc,n)=16B
//  blocks [1024,3072):   softmax rows of feature_logits -> wbF frag-major
// Frag-major: operand fragment of v_mfma_32x32x16 (lane row=col, k=hi*8+j)
// loads as ONE coalesced global_load_dwordx4 from [kc][row] cells.
// ---------------------------------------------------------------------------
__global__ __launch_bounds__(256) void prep(
    const float* __restrict__ x, const float* __restrict__ logits,
    unsigned short* __restrict__ xbF, unsigned short* __restrict__ wbF) {
  if (blockIdx.x < 1024) {
    // --- x transpose-convert: wave w covers 8n x 8kc cells ---
    int w = blockIdx.x * 4 + (threadIdx.x >> 6);
    int l = threadIdx.x & 63;
    int n  = ((w & 511) << 3) + (l >> 3);
    int kc = ((w >> 9) << 3) + (l & 7);
    const float4* p = (const float4*)(x + (size_t)n * F_ + kc * 8);
    float4 a = p[0], b = p[1];
    bf16x8 o;
    o[0] = (short)f2bf(a.x); o[1] = (short)f2bf(a.y);
    o[2] = (short)f2bf(a.z); o[3] = (short)f2bf(a.w);
    o[4] = (short)f2bf(b.x); o[5] = (short)f2bf(b.y);
    o[6] = (short)f2bf(b.z); o[7] = (short)f2bf(b.w);
    *(bf16x8*)(xbF + ((size_t)kc * B_ + n) * 8) = o;
  } else {
    // --- softmax (4 rows/block, wave per row) + LDS transpose to frag-major ---
    __shared__ uint32_t ls[4 * 257];   // [4 rows][257 dw] (+1 dw pad: conflict-free)
    int bj = blockIdx.x - 1024;
    int wv = threadIdx.x >> 6, l = threadIdx.x & 63;
    int m  = bj * 4 + wv;
    const float* src = logits + (size_t)m * F_ + l * 8;
    float4 v0 = *(const float4*)src;
    float4 v1 = *(const float4*)(src + 4);
    float mx = fmaxf(fmaxf(fmaxf(v0.x, v0.y), fmaxf(v0.z, v0.w)),
                     fmaxf(fmaxf(v1.x, v1.y), fmaxf(v1.z, v1.w)));
    #pragma unroll
    for (int s = 32; s >= 1; s >>= 1) mx = fmaxf(mx, __shfl_xor(mx, s, 64));
    float e[8];
    e[0] = __expf(v0.x - mx); e[1] = __expf(v0.y - mx);
    e[2] = __expf(v0.z - mx); e[3] = __expf(v0.w - mx);
    e[4] = __expf(v1.x - mx); e[5] = __expf(v1.y - mx);
    e[6] = __expf(v1.z - mx); e[7] = __expf(v1.w - mx);
    float sm = e[0] + e[1] + e[2] + e[3] + e[4] + e[5] + e[6] + e[7];
    #pragma unroll
    for (int s = 32; s >= 1; s >>= 1) sm += __shfl_xor(sm, s, 64);
    float inv = 1.0f / sm;
    union { bf16x8 v; uint32_t u[4]; } cv;
    #pragma unroll
    for (int i = 0; i < 8; i++) cv.v[i] = (short)f2bf(e[i] * inv);
    #pragma unroll
    for (int j = 0; j < 4; j++) ls[wv * 257 + l * 4 + j] = cv.u[j];
    __syncthreads();
    int kc = threadIdx.x >> 2, mm = threadIdx.x & 3;
    union { uint32_t u[4]; bf16x8 v; } rv;
    #pragma unroll
    for (int j = 0; j < 4; j++) rv.u[j] = ls[mm * 257 + kc * 4 + j];
    *(bf16x8*)(wbF + ((size_t)kc * M_ + bj * 4 + mm) * 8) = rv.v;
  }
}

// ---------------------------------------------------------------------------
// LDS-free, barrier-free MFMA GEMM + fused sigmoid/leaf epilogue.
// C[M][N] = wbF x xbF^T. Block 128m x 256n, 4 waves 2x2, wave tile 64x128 =
// 2x4 of v_mfma_f32_32x32x16_bf16. All operand frags are coalesced
// global_load_dwordx4 from the frag-major arrays; K-loop has no syncthreads.
// C-layout/lane: n=lane&31, d=reg&3, tree_local=2*(reg>>2)+(lane>>5).
// LDS used only to stage the epilogue output for coalesced stores.
// ---------------------------------------------------------------------------
__global__ __launch_bounds__(256, 2) void odst_mfma(
    const unsigned short* __restrict__ wbF,  // frag-major [KC][M] 16B cells
    const unsigned short* __restrict__ xbF,  // frag-major [KC][B] 16B cells
    const float* __restrict__ thr,           // [T][4]
    const float* __restrict__ leaf,          // [T][16]
    float* __restrict__ out) {               // [B][T]
  __shared__ float eb[256 * 34];             // 34816 B epilogue staging

  const int tid  = threadIdx.x;
  const int lane = tid & 63, wid = tid >> 6;
  const int wm = wid >> 1, wn = wid & 1;
  const int m0 = blockIdx.y * 128;
  const int n0 = blockIdx.x * 256;
  const int col = lane & 31, hi = lane >> 5;

  // per-lane fragment base pointers (kc=0); hi selects odd/even 8-chunk
  const unsigned short* ap[2];
  #pragma unroll
  for (int i = 0; i < 2; i++)
    ap[i] = wbF + (size_t)hi * (M_ * 8) +
            (size_t)(m0 + wm * 64 + i * 32 + col) * 8;
  const unsigned short* bp[4];
  #pragma unroll
  for (int j = 0; j < 4; j++)
    bp[j] = xbF + (size_t)hi * (B_ * 8) +
            (size_t)(n0 + wn * 128 + j * 32 + col) * 8;

  f32x16 acc[2][4] = {};

  for (int kc0 = 0; kc0 < KC_; kc0 += 8) {   // 8 kc per iter = K-step 64
    bf16x8 a[4][2], b[4][4];
    #pragma unroll
    for (int ks = 0; ks < 4; ks++) {
      size_t ka = (size_t)(kc0 + ks * 2) * (M_ * 8);
      size_t kb = (size_t)(kc0 + ks * 2) * (B_ * 8);
      a[ks][0] = *(const bf16x8*)(ap[0] + ka);
      a[ks][1] = *(const bf16x8*)(ap[1] + ka);
      b[ks][0] = *(const bf16x8*)(bp[0] + kb);
      b[ks][1] = *(const bf16x8*)(bp[1] + kb);
      b[ks][2] = *(const bf16x8*)(bp[2] + kb);
      b[ks][3] = *(const bf16x8*)(bp[3] + kb);
    }
    #pragma unroll
    for (int ks = 0; ks < 4; ks++)
      #pragma unroll
      for (int i = 0; i < 2; i++)
        #pragma unroll
        for (int j = 0; j < 4; j++)
          acc[i][j] = __builtin_amdgcn_mfma_f32_32x32x16_bf16(
              a[ks][i], b[ks][j], acc[i][j], 0, 0, 0);
  }

  // ---- fused epilogue (in-register sigmoid/leaf), stage via LDS ----
  const float inv_tau = 1.0f / TAU;
  const int t0 = m0 >> 2;
  #pragma unroll
  for (int i = 0; i < 2; i++) {
    #pragma unroll
    for (int g = 0; g < 4; g++) {
      int tl = wm * 16 + i * 8 + 2 * g + hi;          // tree within block [0,32)
      int t  = t0 + tl;
      float4 th  = *(const float4*)(thr + t * 4);
      float4 lf0 = *(const float4*)(leaf + t * 16);
      float4 lf1 = *(const float4*)(leaf + t * 16 + 4);
      float4 lf2 = *(const float4*)(leaf + t * 16 + 8);
      float4 lf3 = *(const float4*)(leaf + t * 16 + 12);
      float c2x = th.x * inv_tau, c2y = th.y * inv_tau,
            c2z = th.z * inv_tau, c2w = th.w * inv_tau;
      #pragma unroll
      for (int j = 0; j < 4; j++) {
        float p0 = __builtin_amdgcn_rcpf(1.0f + __expf(fmaf(acc[i][j][g * 4 + 0], -inv_tau, c2x)));
        float p1 = __builtin_amdgcn_rcpf(1.0f + __expf(fmaf(acc[i][j][g * 4 + 1], -inv_tau, c2y)));
        float p2 = __builtin_amdgcn_rcpf(1.0f + __expf(fmaf(acc[i][j][g * 4 + 2], -inv_tau, c2z)));
        float p3 = __builtin_amdgcn_rcpf(1.0f + __expf(fmaf(acc[i][j][g * 4 + 3], -inv_tau, c2w)));
        float q0 = 1.0f - p0, q1 = 1.0f - p1, q2 = 1.0f - p2, q3 = 1.0f - p3;
        float A0 = lf0.x * q0 + lf0.y * p0;
        float A1 = lf0.z * q0 + lf0.w * p0;
        float A2 = lf1.x * q0 + lf1.y * p0;
        float A3 = lf1.z * q0 + lf1.w * p0;
        float A4 = lf2.x * q0 + lf2.y * p0;
        float A5 = lf2.z * q0 + lf2.w * p0;
        float A6 = lf3.x * q0 + lf3.y * p0;
        float A7 = lf3.z * q0 + lf3.w * p0;
        float B0 = A0 * q1 + A1 * p1;
        float B1 = A2 * q1 + A3 * p1;
        float B2 = A4 * q1 + A5 * p1;
        float B3 = A6 * q1 + A7 * p1;
        float C0 = B0 * q2 + B1 * p2;
        float C1 = B2 * q2 + B3 * p2;
        float o  = C0 * q3 + C1 * p3;
        int bl = wn * 128 + j * 32 + col;              // batch within block
        eb[bl * 34 + tl] = o;                          // stride 34: 2-way (free)
      }
    }
  }
  __syncthreads();

  // coalesced store: 256 batch rows x 32 trees, float2 per thread-slot
  #pragma unroll
  for (int q = 0; q < 16; q++) {
    int row = q * 16 + (tid >> 4);
    int s   = tid & 15;
    float2 v = *(const float2*)(eb + row * 34 + s * 2);
    *(float2*)(out + (size_t)(n0 + row) * T_ + t0 + s * 2) = v;
  }
}

extern "C" void kernel_launch(void* const* d_in, const int* in_sizes, int n_in,
                              void* d_out, int out_size, void* d_ws, size_t ws_size,
                              hipStream_t stream) {
  const float* x    = (const float*)d_in[0];  // (B, F)
  const float* fl   = (const float*)d_in[1];  // (T, D, F)
  const float* thr  = (const float*)d_in[2];  // (T, D)
  const float* leaf = (const float*)d_in[3];  // (T, 16)
  float* out = (float*)d_out;                 // (B, T)

  unsigned short* wbF = (unsigned short*)d_ws;                                // 8 MB
  unsigned short* xbF = (unsigned short*)((char*)d_ws + (size_t)KC_ * M_ * 16); // 4 MB

  prep<<<dim3(1024 + M_ / 4), dim3(256), 0, stream>>>(x, fl, xbF, wbF);
  odst_mfma<<<dim3(B_ / 256, M_ / 128), dim3(256), 0, stream>>>(wbF, xbF, thr, leaf, out);
}

// Round 5
// 139.170 us; speedup vs baseline: 1.0048x; 1.0048x over previous
//
#include <hip/hip_runtime.h>
#include <stdint.h>

#define B_  4096
#define F_  512
#define T_  2048
#define D_  4
#define M_  (T_ * D_)   // 8192 GEMM-M (trees*dims)
#define KC_ (F_ / 8)    // 64 16-byte k-chunks per row
#define TAU 0.2018004745467103f

typedef __attribute__((ext_vector_type(8)))  short bf16x8;
typedef __attribute__((ext_vector_type(16))) float f32x16;

static __device__ __forceinline__ unsigned short f2bf(float f) {
  union { float f; uint32_t u; } v; v.f = f;
  uint32_t r = v.u + 0x7fffu + ((v.u >> 16) & 1u);  // RNE
  return (unsigned short)(r >> 16);
}

// ---------------------------------------------------------------------------
// Prep (single launch, two jobs by blockIdx):
//  blocks [0,1024):      x (B,F) fp32 -> xbF frag-major bf16: cell(kc,n)=16B
//  blocks [1024,3072):   softmax rows of feature_logits -> wbF frag-major
// ---------------------------------------------------------------------------
__global__ __launch_bounds__(256) void prep(
    const float* __restrict__ x, const float* __restrict__ logits,
    unsigned short* __restrict__ xbF, unsigned short* __restrict__ wbF) {
  if (blockIdx.x < 1024) {
    int w = blockIdx.x * 4 + (threadIdx.x >> 6);
    int l = threadIdx.x & 63;
    int n  = ((w & 511) << 3) + (l >> 3);
    int kc = ((w >> 9) << 3) + (l & 7);
    const float4* p = (const float4*)(x + (size_t)n * F_ + kc * 8);
    float4 a = p[0], b = p[1];
    bf16x8 o;
    o[0] = (short)f2bf(a.x); o[1] = (short)f2bf(a.y);
    o[2] = (short)f2bf(a.z); o[3] = (short)f2bf(a.w);
    o[4] = (short)f2bf(b.x); o[5] = (short)f2bf(b.y);
    o[6] = (short)f2bf(b.z); o[7] = (short)f2bf(b.w);
    *(bf16x8*)(xbF + ((size_t)kc * B_ + n) * 8) = o;
  } else {
    __shared__ uint32_t ls[4 * 257];
    int bj = blockIdx.x - 1024;
    int wv = threadIdx.x >> 6, l = threadIdx.x & 63;
    int m  = bj * 4 + wv;
    const float* src = logits + (size_t)m * F_ + l * 8;
    float4 v0 = *(const float4*)src;
    float4 v1 = *(const float4*)(src + 4);
    float mx = fmaxf(fmaxf(fmaxf(v0.x, v0.y), fmaxf(v0.z, v0.w)),
                     fmaxf(fmaxf(v1.x, v1.y), fmaxf(v1.z, v1.w)));
    #pragma unroll
    for (int s = 32; s >= 1; s >>= 1) mx = fmaxf(mx, __shfl_xor(mx, s, 64));
    float e[8];
    e[0] = __expf(v0.x - mx); e[1] = __expf(v0.y - mx);
    e[2] = __expf(v0.z - mx); e[3] = __expf(v0.w - mx);
    e[4] = __expf(v1.x - mx); e[5] = __expf(v1.y - mx);
    e[6] = __expf(v1.z - mx); e[7] = __expf(v1.w - mx);
    float sm = e[0] + e[1] + e[2] + e[3] + e[4] + e[5] + e[6] + e[7];
    #pragma unroll
    for (int s = 32; s >= 1; s >>= 1) sm += __shfl_xor(sm, s, 64);
    float inv = 1.0f / sm;
    union { bf16x8 v; uint32_t u[4]; } cv;
    #pragma unroll
    for (int i = 0; i < 8; i++) cv.v[i] = (short)f2bf(e[i] * inv);
    #pragma unroll
    for (int j = 0; j < 4; j++) ls[wv * 257 + l * 4 + j] = cv.u[j];
    __syncthreads();
    int kc = threadIdx.x >> 2, mm = threadIdx.x & 3;
    union { uint32_t u[4]; bf16x8 v; } rv;
    #pragma unroll
    for (int j = 0; j < 4; j++) rv.u[j] = ls[mm * 257 + kc * 4 + j];
    *(bf16x8*)(wbF + ((size_t)kc * M_ + bj * 4 + mm) * 8) = rv.v;
  }
}

// ---------------------------------------------------------------------------
// Barrier-free MFMA GEMM, register ring-buffer software pipeline.
// Block 128m x 256n, 4 waves 2x2, wave tile 64x128 = 2x4 of
// v_mfma_f32_32x32x16_bf16. K-loop: 32 steps of K=16; step s consumes
// frag-major cell kc=2s+hi. Ring of 3 frag slots, prefetch distance 2:
// loads for s+2 issue before MFMAs of s -> each load has >=512 cyc lead,
// no barrier ever drains vmcnt. LDS only stages the epilogue output.
// C-layout/lane: n=lane&31, d=reg&3, tree_local=2*(reg>>2)+(lane>>5).
// ---------------------------------------------------------------------------
__global__ __launch_bounds__(256, 2) void odst_mfma(
    const unsigned short* __restrict__ wbF,  // frag-major [KC][M] 16B cells
    const unsigned short* __restrict__ xbF,  // frag-major [KC][B] 16B cells
    const float* __restrict__ thr,           // [T][4]
    const float* __restrict__ leaf,          // [T][16]
    float* __restrict__ out) {               // [B][T]
  __shared__ float eb[256 * 34];             // 34816 B epilogue staging

  const int tid  = threadIdx.x;
  const int lane = tid & 63, wid = tid >> 6;
  const int wm = wid >> 1, wn = wid & 1;
  const int m0 = blockIdx.y * 128;
  const int n0 = blockIdx.x * 256;
  const int col = lane & 31, hi = lane >> 5;

  const unsigned short* ap[2];
  #pragma unroll
  for (int i = 0; i < 2; i++)
    ap[i] = wbF + (size_t)hi * (M_ * 8) +
            (size_t)(m0 + wm * 64 + i * 32 + col) * 8;
  const unsigned short* bp[4];
  #pragma unroll
  for (int j = 0; j < 4; j++)
    bp[j] = xbF + (size_t)hi * (B_ * 8) +
            (size_t)(n0 + wn * 128 + j * 32 + col) * 8;

  f32x16 acc[2][4] = {};
  bf16x8 ar[3][2], br[3][4];

#define LOAD_SLOT(s, r) do {                                   \
    size_t ka = (size_t)(2 * (s)) * (M_ * 8);                  \
    size_t kb = (size_t)(2 * (s)) * (B_ * 8);                  \
    ar[r][0] = *(const bf16x8*)(ap[0] + ka);                   \
    ar[r][1] = *(const bf16x8*)(ap[1] + ka);                   \
    br[r][0] = *(const bf16x8*)(bp[0] + kb);                   \
    br[r][1] = *(const bf16x8*)(bp[1] + kb);                   \
    br[r][2] = *(const bf16x8*)(bp[2] + kb);                   \
    br[r][3] = *(const bf16x8*)(bp[3] + kb);                   \
  } while (0)

  LOAD_SLOT(0, 0);
  LOAD_SLOT(1, 1);
  #pragma unroll
  for (int s = 0; s < 32; s++) {
    if (s + 2 < 32) LOAD_SLOT(s + 2, (s + 2) % 3);
    const int r = s % 3;
    #pragma unroll
    for (int i = 0; i < 2; i++)
      #pragma unroll
      for (int j = 0; j < 4; j++)
        acc[i][j] = __builtin_amdgcn_mfma_f32_32x32x16_bf16(
            ar[r][i], br[r][j], acc[i][j], 0, 0, 0);
  }
#undef LOAD_SLOT

  // ---- fused epilogue (in-register sigmoid/leaf), stage via LDS ----
  const float inv_tau = 1.0f / TAU;
  const int t0 = m0 >> 2;
  #pragma unroll
  for (int i = 0; i < 2; i++) {
    #pragma unroll
    for (int g = 0; g < 4; g++) {
      int tl = wm * 16 + i * 8 + 2 * g + hi;          // tree within block [0,32)
      int t  = t0 + tl;
      float4 th  = *(const float4*)(thr + t * 4);
      float4 lf0 = *(const float4*)(leaf + t * 16);
      float4 lf1 = *(const float4*)(leaf + t * 16 + 4);
      float4 lf2 = *(const float4*)(leaf + t * 16 + 8);
      float4 lf3 = *(const float4*)(leaf + t * 16 + 12);
      float c2x = th.x * inv_tau, c2y = th.y * inv_tau,
            c2z = th.z * inv_tau, c2w = th.w * inv_tau;
      #pragma unroll
      for (int j = 0; j < 4; j++) {
        float p0 = __builtin_amdgcn_rcpf(1.0f + __expf(fmaf(acc[i][j][g * 4 + 0], -inv_tau, c2x)));
        float p1 = __builtin_amdgcn_rcpf(1.0f + __expf(fmaf(acc[i][j][g * 4 + 1], -inv_tau, c2y)));
        float p2 = __builtin_amdgcn_rcpf(1.0f + __expf(fmaf(acc[i][j][g * 4 + 2], -inv_tau, c2z)));
        float p3 = __builtin_amdgcn_rcpf(1.0f + __expf(fmaf(acc[i][j][g * 4 + 3], -inv_tau, c2w)));
        float q0 = 1.0f - p0, q1 = 1.0f - p1, q2 = 1.0f - p2, q3 = 1.0f - p3;
        float A0 = lf0.x * q0 + lf0.y * p0;
        float A1 = lf0.z * q0 + lf0.w * p0;
        float A2 = lf1.x * q0 + lf1.y * p0;
        float A3 = lf1.z * q0 + lf1.w * p0;
        float A4 = lf2.x * q0 + lf2.y * p0;
        float A5 = lf2.z * q0 + lf2.w * p0;
        float A6 = lf3.x * q0 + lf3.y * p0;
        float A7 = lf3.z * q0 + lf3.w * p0;
        float B0 = A0 * q1 + A1 * p1;
        float B1 = A2 * q1 + A3 * p1;
        float B2 = A4 * q1 + A5 * p1;
        float B3 = A6 * q1 + A7 * p1;
        float C0 = B0 * q2 + B1 * p2;
        float C1 = B2 * q2 + B3 * p2;
        float o  = C0 * q3 + C1 * p3;
        int bl = wn * 128 + j * 32 + col;              // batch within block
        eb[bl * 34 + tl] = o;                          // stride 34: 2-way (free)
      }
    }
  }
  __syncthreads();

  // coalesced store: 256 batch rows x 32 trees, float2 per thread-slot
  #pragma unroll
  for (int q = 0; q < 16; q++) {
    int row = q * 16 + (tid >> 4);
    int s   = tid & 15;
    float2 v = *(const float2*)(eb + row * 34 + s * 2);
    *(float2*)(out + (size_t)(n0 + row) * T_ + t0 + s * 2) = v;
  }
}

extern "C" void kernel_launch(void* const* d_in, const int* in_sizes, int n_in,
                              void* d_out, int out_size, void* d_ws, size_t ws_size,
                              hipStream_t stream) {
  const float* x    = (const float*)d_in[0];  // (B, F)
  const float* fl   = (const float*)d_in[1];  // (T, D, F)
  const float* thr  = (const float*)d_in[2];  // (T, D)
  const float* leaf = (const float*)d_in[3];  // (T, 16)
  float* out = (float*)d_out;                 // (B, T)

  unsigned short* wbF = (unsigned short*)d_ws;                                  // 8 MB
  unsigned short* xbF = (unsigned short*)((char*)d_ws + (size_t)KC_ * M_ * 16); // 4 MB

  prep<<<dim3(1024 + M_ / 4), dim3(256), 0, stream>>>(x, fl, xbF, wbF);
  odst_mfma<<<dim3(B_ / 256, M_ / 128), dim3(256), 0, stream>>>(wbF, xbF, thr, leaf, out);
}

// Round 6
// 130.857 us; speedup vs baseline: 1.0687x; 1.0635x over previous
//
#include <hip/hip_runtime.h>
#include <stdint.h>

#define B_  4096
#define F_  512
#define T_  2048
#define D_  4
#define M_  (T_ * D_)   // 8192 GEMM-M (trees*dims)
#define KC_ (F_ / 8)    // 64 16-byte k-chunks per row
#define TAU 0.2018004745467103f

typedef __attribute__((ext_vector_type(8)))  short bf16x8;
typedef __attribute__((ext_vector_type(16))) float f32x16;

static __device__ __forceinline__ unsigned short f2bf(float f) {
  union { float f; uint32_t u; } v; v.f = f;
  uint32_t r = v.u + 0x7fffu + ((v.u >> 16) & 1u);  // RNE
  return (unsigned short)(r >> 16);
}

// ---------------------------------------------------------------------------
// Prep (single launch, two jobs by blockIdx):
//  blocks [0,1024):      x (B,F) fp32 -> xbF frag-major bf16: cell(kc,n)=16B
//  blocks [1024,3072):   softmax rows of feature_logits -> wbF frag-major
// ---------------------------------------------------------------------------
__global__ __launch_bounds__(256) void prep(
    const float* __restrict__ x, const float* __restrict__ logits,
    unsigned short* __restrict__ xbF, unsigned short* __restrict__ wbF) {
  if (blockIdx.x < 1024) {
    int w = blockIdx.x * 4 + (threadIdx.x >> 6);
    int l = threadIdx.x & 63;
    int n  = ((w & 511) << 3) + (l >> 3);
    int kc = ((w >> 9) << 3) + (l & 7);
    const float4* p = (const float4*)(x + (size_t)n * F_ + kc * 8);
    float4 a = p[0], b = p[1];
    bf16x8 o;
    o[0] = (short)f2bf(a.x); o[1] = (short)f2bf(a.y);
    o[2] = (short)f2bf(a.z); o[3] = (short)f2bf(a.w);
    o[4] = (short)f2bf(b.x); o[5] = (short)f2bf(b.y);
    o[6] = (short)f2bf(b.z); o[7] = (short)f2bf(b.w);
    *(bf16x8*)(xbF + ((size_t)kc * B_ + n) * 8) = o;
  } else {
    __shared__ uint32_t ls[4 * 257];
    int bj = blockIdx.x - 1024;
    int wv = threadIdx.x >> 6, l = threadIdx.x & 63;
    int m  = bj * 4 + wv;
    const float* src = logits + (size_t)m * F_ + l * 8;
    float4 v0 = *(const float4*)src;
    float4 v1 = *(const float4*)(src + 4);
    float mx = fmaxf(fmaxf(fmaxf(v0.x, v0.y), fmaxf(v0.z, v0.w)),
                     fmaxf(fmaxf(v1.x, v1.y), fmaxf(v1.z, v1.w)));
    #pragma unroll
    for (int s = 32; s >= 1; s >>= 1) mx = fmaxf(mx, __shfl_xor(mx, s, 64));
    float e[8];
    e[0] = __expf(v0.x - mx); e[1] = __expf(v0.y - mx);
    e[2] = __expf(v0.z - mx); e[3] = __expf(v0.w - mx);
    e[4] = __expf(v1.x - mx); e[5] = __expf(v1.y - mx);
    e[6] = __expf(v1.z - mx); e[7] = __expf(v1.w - mx);
    float sm = e[0] + e[1] + e[2] + e[3] + e[4] + e[5] + e[6] + e[7];
    #pragma unroll
    for (int s = 32; s >= 1; s >>= 1) sm += __shfl_xor(sm, s, 64);
    float inv = 1.0f / sm;
    union { bf16x8 v; uint32_t u[4]; } cv;
    #pragma unroll
    for (int i = 0; i < 8; i++) cv.v[i] = (short)f2bf(e[i] * inv);
    #pragma unroll
    for (int j = 0; j < 4; j++) ls[wv * 257 + l * 4 + j] = cv.u[j];
    __syncthreads();
    int kc = threadIdx.x >> 2, mm = threadIdx.x & 3;
    union { uint32_t u[4]; bf16x8 v; } rv;
    #pragma unroll
    for (int j = 0; j < 4; j++) rv.u[j] = ls[mm * 257 + kc * 4 + j];
    *(bf16x8*)(wbF + ((size_t)kc * M_ + bj * 4 + mm) * 8) = rv.v;
  }
}

// ---------------------------------------------------------------------------
// Hybrid MFMA GEMM: A (weights) staged to LDS in BK=128 chunks via
// global_load_lds (frag-major cells, only 4 stage-barriers total); B (x)
// loaded frag-major from global with a distance-2 register ring.
// Block 128m x 256n, 4 waves 2x2, wave tile 64x128 = 2x4 of
// v_mfma_f32_32x32x16_bf16 per K=16 step; 32 steps total.
// C-layout/lane: n=lane&31, d=reg&3, tree_local=2*(reg>>2)+(lane>>5).
// Grid: x = m-blocks (64), y = n-blocks (16) -> consecutive blocks share
// the same B tile (L2/XCD locality).
// ---------------------------------------------------------------------------
__global__ __launch_bounds__(256, 2) void odst_mfma(
    const unsigned short* __restrict__ wbF,  // frag-major [KC][M] 16B cells
    const unsigned short* __restrict__ xbF,  // frag-major [KC][B] 16B cells
    const float* __restrict__ thr,           // [T][4]
    const float* __restrict__ leaf,          // [T][16]
    float* __restrict__ out) {               // [B][T]
  __shared__ __align__(16) char smem[34816];
  unsigned short* As = (unsigned short*)smem;   // [16 kc][128 m] 16B cells = 32KB
  float* eb = (float*)smem;                     // epilogue staging [256][34]

  const int tid  = threadIdx.x;
  const int lane = tid & 63, wid = tid >> 6;
  const int wm = wid >> 1, wn = wid & 1;
  const int m0 = blockIdx.x * 128;              // grid swapped: x = m
  const int n0 = blockIdx.y * 256;
  const int col = lane & 31, hi = lane >> 5;

  const unsigned short* bp[4];
  #pragma unroll
  for (int j = 0; j < 4; j++)
    bp[j] = xbF + (size_t)hi * (B_ * 8) +
            (size_t)(n0 + wn * 128 + j * 32 + col) * 8;

  f32x16 acc[2][4] = {};
  bf16x8 br[3][4];

#define LOADB(g, r) do {                                       \
    size_t kb = (size_t)(2 * (g)) * (B_ * 8);                  \
    br[r][0] = *(const bf16x8*)(bp[0] + kb);                   \
    br[r][1] = *(const bf16x8*)(bp[1] + kb);                   \
    br[r][2] = *(const bf16x8*)(bp[2] + kb);                   \
    br[r][3] = *(const bf16x8*)(bp[3] + kb);                   \
  } while (0)

  LOADB(0, 0);
  LOADB(1, 1);

  #pragma unroll
  for (int it = 0; it < 4; it++) {
    __syncthreads();                      // protect As overwrite
    // stage A chunk: 16 kc x 128 m cells, 8 global_load_lds per wave
    const int kc0 = it * 16;
    #pragma unroll
    for (int q = 0; q < 8; q++) {
      int cbase = q * 256 + wid * 64;     // wave-uniform cell base
      int c = cbase + lane;               // per-lane cell (64 consecutive m)
      const unsigned short* src =
          wbF + ((size_t)(kc0 + (c >> 7)) * M_ + m0 + (c & 127)) * 8;
      __builtin_amdgcn_global_load_lds(
          (const __attribute__((address_space(1))) uint32_t*)src,
          (__attribute__((address_space(3))) uint32_t*)(As + (size_t)cbase * 8),
          16, 0, 0);
    }
    __syncthreads();                      // drain stage (4x per kernel only)

    #pragma unroll
    for (int s = 0; s < 8; s++) {
      const int g = it * 8 + s;           // global K-step
      if (g + 2 < 32) LOADB(g + 2, (g + 2) % 3);
      const int r = g % 3;
      bf16x8 a[2];
      #pragma unroll
      for (int i = 0; i < 2; i++)
        a[i] = *(const bf16x8*)(As + (((2 * s + hi) << 7) + wm * 64 + i * 32 + col) * 8);
      #pragma unroll
      for (int i = 0; i < 2; i++)
        #pragma unroll
        for (int j = 0; j < 4; j++)
          acc[i][j] = __builtin_amdgcn_mfma_f32_32x32x16_bf16(
              a[i], br[r][j], acc[i][j], 0, 0, 0);
    }
  }
#undef LOADB

  __syncthreads();  // all ds_reads of As done before eb overwrites it

  // ---- fused epilogue (in-register sigmoid/leaf), stage via LDS ----
  const float inv_tau = 1.0f / TAU;
  const int t0 = m0 >> 2;
  #pragma unroll
  for (int i = 0; i < 2; i++) {
    #pragma unroll
    for (int g = 0; g < 4; g++) {
      int tl = wm * 16 + i * 8 + 2 * g + hi;          // tree within block [0,32)
      int t  = t0 + tl;
      float4 th  = *(const float4*)(thr + t * 4);
      float4 lf0 = *(const float4*)(leaf + t * 16);
      float4 lf1 = *(const float4*)(leaf + t * 16 + 4);
      float4 lf2 = *(const float4*)(leaf + t * 16 + 8);
      float4 lf3 = *(const float4*)(leaf + t * 16 + 12);
      float c2x = th.x * inv_tau, c2y = th.y * inv_tau,
            c2z = th.z * inv_tau, c2w = th.w * inv_tau;
      #pragma unroll
      for (int j = 0; j < 4; j++) {
        float p0 = __builtin_amdgcn_rcpf(1.0f + __expf(fmaf(acc[i][j][g * 4 + 0], -inv_tau, c2x)));
        float p1 = __builtin_amdgcn_rcpf(1.0f + __expf(fmaf(acc[i][j][g * 4 + 1], -inv_tau, c2y)));
        float p2 = __builtin_amdgcn_rcpf(1.0f + __expf(fmaf(acc[i][j][g * 4 + 2], -inv_tau, c2z)));
        float p3 = __builtin_amdgcn_rcpf(1.0f + __expf(fmaf(acc[i][j][g * 4 + 3], -inv_tau, c2w)));
        float q0 = 1.0f - p0, q1 = 1.0f - p1, q2 = 1.0f - p2, q3 = 1.0f - p3;
        float A0 = lf0.x * q0 + lf0.y * p0;
        float A1 = lf0.z * q0 + lf0.w * p0;
        float A2 = lf1.x * q0 + lf1.y * p0;
        float A3 = lf1.z * q0 + lf1.w * p0;
        float A4 = lf2.x * q0 + lf2.y * p0;
        float A5 = lf2.z * q0 + lf2.w * p0;
        float A6 = lf3.x * q0 + lf3.y * p0;
        float A7 = lf3.z * q0 + lf3.w * p0;
        float B0 = A0 * q1 + A1 * p1;
        float B1 = A2 * q1 + A3 * p1;
        float B2 = A4 * q1 + A5 * p1;
        float B3 = A6 * q1 + A7 * p1;
        float C0 = B0 * q2 + B1 * p2;
        float C1 = B2 * q2 + B3 * p2;
        float o  = C0 * q3 + C1 * p3;
        int bl = wn * 128 + j * 32 + col;              // batch within block
        eb[bl * 34 + tl] = o;                          // stride 34: 2-way (free)
      }
    }
  }
  __syncthreads();

  // coalesced store: 256 batch rows x 32 trees, float2 per thread-slot
  #pragma unroll
  for (int q = 0; q < 16; q++) {
    int row = q * 16 + (tid >> 4);
    int s   = tid & 15;
    float2 v = *(const float2*)(eb + row * 34 + s * 2);
    *(float2*)(out + (size_t)(n0 + row) * T_ + t0 + s * 2) = v;
  }
}

extern "C" void kernel_launch(void* const* d_in, const int* in_sizes, int n_in,
                              void* d_out, int out_size, void* d_ws, size_t ws_size,
                              hipStream_t stream) {
  const float* x    = (const float*)d_in[0];  // (B, F)
  const float* fl   = (const float*)d_in[1];  // (T, D, F)
  const float* thr  = (const float*)d_in[2];  // (T, D)
  const float* leaf = (const float*)d_in[3];  // (T, 16)
  float* out = (float*)d_out;                 // (B, T)

  unsigned short* wbF = (unsigned short*)d_ws;                                  // 8 MB
  unsigned short* xbF = (unsigned short*)((char*)d_ws + (size_t)KC_ * M_ * 16); // 4 MB

  prep<<<dim3(1024 + M_ / 4), dim3(256), 0, stream>>>(x, fl, xbF, wbF);
  odst_mfma<<<dim3(M_ / 128, B_ / 256), dim3(256), 0, stream>>>(wbF, xbF, thr, leaf, out);
}